// Round 9
// baseline (198.541 us; speedup 1.0000x reference)
//
#include <hip/hip_runtime.h>
#include <hip/hip_bf16.h>

// SelectiveSSM: B=1, L=2048, D_MODEL=512, D_INNER=1024, D_STATE=16, D_CONV=4
// ESTABLISHED: inputs fp32, d_out fp32, ws >= 17.05MB (R6 fp32 path ran).
// R17 (216us): scan serial-chain fix. R20 (221us): scan floor 62us, no spill.
// R21 (218us): dbuf gload_lds GEMMs. R22/R23 (190us, WIN): 9->7 dispatches,
// xproj split-K -> per-dispatch overhead ~6-12us confirmed.
// R24 (197us, FAILED): xproj fused into conv's tail = +13us serial work >
// boundary saved. Lesson: only fuse into IDLE capacity.
// R25: revert conv/xproj/prep to R23; remove the GATE dispatch instead:
//  - gemm1 split epilogue: x-half -> compact xc[l][1024]; z-half -> zT[d][l]
//    (transposed 8B stores; block-uniform branch on col0)
//  - scan gates in its store loop: ys = sys_fp32 * silu(zT row) (one fewer
//    bf16 rounding of y than R23's gate)
//  - gemm2 self-staging: A transpose-staged from gated ysT, B transpose-cast
//    from W_out fp32 per K-step (same-bx blocks share XCD -> panel L2-hits);
//    WoutT buffer + WT transpose deleted.
// 6 dispatches: prep, gemm1, conv, xproj, scan, gemm2.
// ws 16.26MB: xc 4@0 | zT 4@4 | buf1(xs) 4@8 | WinT@12+xbf@14 -> xsT 4@12 |
// xpcT 264KB@16MB.

#define L_SEQ 2048
#define DM 512
#define DI 1024
#define DS 16
#define NXP 33
#define EPS 1e-10f
#define RCPEPS 1e10f
#define LOG2E 1.44269504088896340736f
#define LN2 0.69314718055994530942f
#define LOG2EPS -33.219280948873623478f  // log2(1e-10)

typedef __hip_bfloat16 bf16;
typedef __attribute__((ext_vector_type(8))) short bf16x8v;
typedef __attribute__((ext_vector_type(4))) float f32x4v;
typedef __attribute__((ext_vector_type(4))) unsigned int u32x4v;

__device__ __forceinline__ float fexp2(float x) { return __builtin_amdgcn_exp2f(x); }
__device__ __forceinline__ float frcp(float x) { return __builtin_amdgcn_rcpf(x); }

__device__ __forceinline__ void load8(const float* p, float* v) {
  float4 a = *(const float4*)p;
  float4 b = *(const float4*)(p + 4);
  v[0] = a.x; v[1] = a.y; v[2] = a.z; v[3] = a.w;
  v[4] = b.x; v[5] = b.y; v[6] = b.z; v[7] = b.w;
}

// ---------- prep: W_in^T (blocks 0..1023) + x cast (1024..1535) ----------
__global__ __launch_bounds__(256)
void prep_kernel(const float* __restrict__ W_in, bf16* __restrict__ WinT,
                 const float* __restrict__ x, bf16* __restrict__ xbf) {
  __shared__ float tile[32][33];
  int b = blockIdx.x;
  if (b < 1024) {
    int c0 = (b & 63) * 32, r0 = (b >> 6) * 32;  // C=2048 (64 tiles), R=512 (16)
    int tx = threadIdx.x & 31, ty = threadIdx.x >> 5;
#pragma unroll
    for (int i = 0; i < 4; ++i) {
      int rr = ty + i * 8;
      tile[rr][tx] = W_in[(size_t)(r0 + rr) * (2 * DI) + c0 + tx];
    }
    __syncthreads();
#pragma unroll
    for (int i = 0; i < 4; ++i) {
      int cc = ty + i * 8;
      WinT[(size_t)(c0 + cc) * DM + r0 + tx] = __float2bfloat16(tile[tx][cc]);
    }
  } else {
    int i = (b - 1024) * 256 + threadIdx.x;  // < 131072 = L*DM/8 exactly
    float v[8];
    load8(x + (size_t)i * 8, v);
    bf16 o[8];
#pragma unroll
    for (int j = 0; j < 8; ++j) o[j] = __float2bfloat16(v[j]);
    *(uint4*)(xbf + (size_t)i * 8) = *(uint4*)o;
  }
}

// ---------- gemm1: xz = x @ W_in, split epilogue ----------
// 128x128 tile, grid (16,16). bx<8 -> xc[l][1024]; bx>=8 -> zT[n-1024][l].
__global__ __launch_bounds__(256)
void gemm1_kernel(const bf16* __restrict__ A, const bf16* __restrict__ BT,
                  bf16* __restrict__ xc, bf16* __restrict__ zT) {
  constexpr int WM = 4, WN = 4, BM = 128, BN = 128, K = DM;
  __shared__ __align__(16) bf16 As[2][BM * 32];
  __shared__ __align__(16) bf16 Bs[2][BN * 32];
  const int tid = threadIdx.x;
  const int wave = tid >> 6, lane = tid & 63;
  const int q = lane >> 4, r = lane & 15;
  const int wr = wave >> 1, wc = wave & 1;
  const int row0 = blockIdx.y * BM, col0 = blockIdx.x * BN;
  f32x4v acc[WM][WN] = {};
  const int nt = K / 32;

  auto stage = [&](int buf, int t) {
    int k0 = t * 32;
#pragma unroll
    for (int i = 0; i < BM / 64; ++i) {
      int slot = tid + i * 256;
      int row = slot >> 2, seg = slot & 3;
      __builtin_amdgcn_global_load_lds(
          (const __attribute__((address_space(1))) void*)(
              A + (size_t)(row0 + row) * DM + k0 + seg * 8),
          (__attribute__((address_space(3))) void*)&As[buf][row * 32 + seg * 8],
          16, 0, 0);
    }
#pragma unroll
    for (int i = 0; i < BN / 64; ++i) {
      int slot = tid + i * 256;
      int row = slot >> 2, seg = slot & 3;
      __builtin_amdgcn_global_load_lds(
          (const __attribute__((address_space(1))) void*)(
              BT + (size_t)(col0 + row) * K + k0 + seg * 8),
          (__attribute__((address_space(3))) void*)&Bs[buf][row * 32 + seg * 8],
          16, 0, 0);
    }
  };

  stage(0, 0);
  __syncthreads();
  int cur = 0;
  for (int t = 0; t < nt; ++t) {
    if (t + 1 < nt) stage(cur ^ 1, t + 1);
    bf16x8v a[WM], b[WN];
#pragma unroll
    for (int m = 0; m < WM; ++m)
      a[m] = *(const bf16x8v*)&As[cur][(wr * WM * 16 + m * 16 + r) * 32 + q * 8];
#pragma unroll
    for (int n = 0; n < WN; ++n)
      b[n] = *(const bf16x8v*)&Bs[cur][(wc * WN * 16 + n * 16 + r) * 32 + q * 8];
#pragma unroll
    for (int m = 0; m < WM; ++m)
#pragma unroll
      for (int n = 0; n < WN; ++n)
        acc[m][n] = __builtin_amdgcn_mfma_f32_16x16x32_bf16(a[m], b[n],
                                                            acc[m][n], 0, 0, 0);
    __syncthreads();
    cur ^= 1;
  }
  if (col0 < DI) {
    // x-half: xc[l][n], ld 1024
#pragma unroll
    for (int m = 0; m < WM; ++m)
#pragma unroll
      for (int n = 0; n < WN; ++n)
#pragma unroll
        for (int reg = 0; reg < 4; ++reg) {
          int mm = row0 + wr * WM * 16 + m * 16 + q * 4 + reg;
          int nn = col0 + wc * WN * 16 + n * 16 + r;
          xc[(size_t)mm * DI + nn] = __float2bfloat16(acc[m][n][reg]);
        }
  } else {
    // z-half: zT[nn-1024][l], 4 consecutive l per (m,n) -> packed 8B store
#pragma unroll
    for (int m = 0; m < WM; ++m)
#pragma unroll
      for (int n = 0; n < WN; ++n) {
        int mm = row0 + wr * WM * 16 + m * 16 + q * 4;
        int nn = col0 - DI + wc * WN * 16 + n * 16 + r;
        bf16 o[4];
#pragma unroll
        for (int reg = 0; reg < 4; ++reg) o[reg] = __float2bfloat16(acc[m][n][reg]);
        *(uint2*)(zT + (size_t)nn * L_SEQ + mm) = *(uint2*)o;
      }
  }
}

// ---------- xproj split-K (R23-proven): xpcT[j][l] += partial ----------
__global__ __launch_bounds__(256)
void gemm_xproj_sk(const bf16* __restrict__ A, const float* __restrict__ Wx,
                   float* __restrict__ xpcT) {
  __shared__ __align__(16) bf16 As[64 * 40];
  __shared__ __align__(16) bf16 Bs[64 * 40];
  const int tid = threadIdx.x;
  const int wave = tid >> 6, lane = tid & 63;
  const int q = lane >> 4, r = lane & 15;
  const int row0 = blockIdx.y * 64;
  const int kb = blockIdx.x * 128;
  const int srow = tid >> 2, sseg = tid & 3;
  f32x4v acc[4] = {};
  for (int k0 = kb; k0 < kb + 128; k0 += 32) {
    *(uint4*)&As[srow * 40 + sseg * 8] =
        *(const uint4*)(A + (size_t)(row0 + srow) * DI + k0 + sseg * 8);
    int k = tid >> 3, n0 = (tid & 7) * 8;
#pragma unroll
    for (int j = 0; j < 8; ++j) {
      int n = n0 + j;
      float v = (n < NXP) ? Wx[(size_t)(k0 + k) * NXP + n] : 0.f;
      Bs[n * 40 + k] = __float2bfloat16(v);
    }
    __syncthreads();
    bf16x8v a = *(const bf16x8v*)&As[(wave * 16 + r) * 40 + q * 8];
#pragma unroll
    for (int j = 0; j < 4; ++j) {
      bf16x8v b = *(const bf16x8v*)&Bs[(j * 16 + r) * 40 + q * 8];
      acc[j] = __builtin_amdgcn_mfma_f32_16x16x32_bf16(a, b, acc[j], 0, 0, 0);
    }
    __syncthreads();
  }
#pragma unroll
  for (int j = 0; j < 4; ++j)
#pragma unroll
    for (int reg = 0; reg < 4; ++reg) {
      int m = row0 + wave * 16 + q * 4 + reg;
      int n = j * 16 + r;
      if (n < NXP) atomicAdd(&xpcT[(size_t)n * L_SEQ + m], acc[j][reg]);
    }
}

// ---------- conv + silu, dual-layout output; zeroes xpcT (R23-proven) ----
// Reads xc (ld 1024). grid (DI/64, L/64), 256 threads.
__global__ __launch_bounds__(256)
void conv_silu_dual(const bf16* __restrict__ xc, const float* __restrict__ conv_w,
                    const float* __restrict__ conv_b, bf16* __restrict__ xs,
                    bf16* __restrict__ xsT, float* __restrict__ xpcT) {
  __shared__ bf16 tile[67][72];   // rows l0-3 .. l0+63
  __shared__ bf16 sout[64][72];   // [d][l]
  const int tid = threadIdx.x;
  const int d0 = blockIdx.x * 64, l0 = blockIdx.y * 64;
  {
    int zb = blockIdx.y * gridDim.x + blockIdx.x;
    if (tid < 132) xpcT[(size_t)zb * 132 + tid] = 0.f;
  }
  for (int slot = tid; slot < 67 * 8; slot += 256) {
    int rr = slot >> 3, seg = slot & 7;
    int l = l0 - 3 + rr;
    uint4 v = {0, 0, 0, 0};
    if (l >= 0) v = *(const uint4*)(xc + (size_t)l * DI + d0 + seg * 8);
    *(uint4*)&tile[rr][seg * 8] = v;
  }
  __syncthreads();
  {
    int lr = tid >> 3, c0t = (tid & 7) * 8;
#pragma unroll
    for (int half = 0; half < 2; ++half) {
      int lrow = lr + half * 32;
      bf16 o[8];
#pragma unroll
      for (int j = 0; j < 8; ++j) {
        int c = c0t + j;
        float acc = conv_b[d0 + c];
#pragma unroll
        for (int k = 0; k < 4; ++k)
          acc = fmaf(__bfloat162float(tile[lrow + k][c]), conv_w[(d0 + c) * 4 + k], acc);
        float v = acc / (1.f + __expf(-acc));
        o[j] = __float2bfloat16(v);
        sout[c][lrow] = o[j];
      }
      *(uint4*)(xs + (size_t)(l0 + lrow) * DI + d0 + c0t) = *(uint4*)o;
    }
  }
  __syncthreads();
  for (int slot = tid; slot < 64 * 8; slot += 256) {
    int dd = slot >> 3, seg = slot & 7;
    *(uint4*)(xsT + (size_t)(d0 + dd) * L_SEQ + l0 + seg * 8) =
        *(uint4*)&sout[dd][seg * 8];
  }
}

// ---------- chunk-parallel scan + fused gate ----------
// R20 structure; store loop now reads zT row and applies ys = y*silu(z).
#define LC 512
#define NW 16
#define SPW 32
#define PSX 513
#define LCP 516

__global__ __launch_bounds__(1024)
void scan_kernel(bf16* __restrict__ xsT, const float* __restrict__ xpcT,
                 const bf16* __restrict__ zT,
                 const float* __restrict__ dt_w, const float* __restrict__ dt_b,
                 const float* __restrict__ A_log, const float* __restrict__ Dvec) {
  __shared__ float sxpT[NXP * PSX];
  __shared__ float sdt[4 * LCP], sg[4 * LCP], sxs[4 * LCP];
  __shared__ float sys[4 * LCP];
  __shared__ float Wtot[NW][64], Vtot[NW][64];
  const int tid = threadIdx.x;
  const int wave = tid >> 6, lane = tid & 63;
  const int s = lane & 15, dl = lane >> 4;
  const int d0 = blockIdx.x * 4;
  const int base = wave * SPW;
  const float As2 = -expf(A_log[s]) * LOG2E;
  const float Dd = Dvec[d0 + dl];
  float dtw[4], dtb[4];
#pragma unroll
  for (int c = 0; c < 4; ++c) {
    dtw[c] = dt_w[d0 + c];
    dtb[c] = dt_b[d0 + c];
  }
  float cs2_carry = 0.f, S_carry = 0.f;
  for (int l0 = 0; l0 < L_SEQ; l0 += LC) {
    for (int idx = tid; idx < NXP * LC; idx += 1024) {
      int u = __builtin_amdgcn_readfirstlane(idx & ~63);
      int j = u >> 9, lb = u & (LC - 1);
      const float* gp = xpcT + (size_t)j * L_SEQ + l0 + lb + lane;
      __builtin_amdgcn_global_load_lds(
          (const __attribute__((address_space(1))) void*)gp,
          (__attribute__((address_space(3))) void*)&sxpT[j * PSX + lb], 4, 0, 0);
    }
    for (int slot = tid; slot < 4 * (LC / 8); slot += 1024) {
      int c = slot >> 6, seg = slot & 63;
      bf16 tmp[8];
      *(uint4*)tmp = *(const uint4*)(xsT + (size_t)(d0 + c) * L_SEQ + l0 + seg * 8);
#pragma unroll
      for (int j = 0; j < 8; ++j) sxs[c * LCP + seg * 8 + j] = __bfloat162float(tmp[j]);
    }
    __syncthreads();
    for (int idx = tid; idx < 4 * LC; idx += 1024) {
      int c = idx >> 9, i = idx & (LC - 1);
      float x0 = sxpT[i];
      float a = fmaf(x0, dtw[c], dtb[c]);
      float dt = __log2f(1.f + fexp2(a * LOG2E)) * LN2;
      sdt[c * LCP + i] = dt;
      sg[c * LCP + i] = dt * sxs[c * LCP + i];
    }
    __syncthreads();
    float P[SPW];
    float Wl = 0.f;
#pragma unroll
    for (int k = 0; k < SPW; ++k) {
      float u = sdt[dl * LCP + base + k] * As2;
      P[k] = Wl;
      Wl += fmaxf(u, LOG2EPS);
    }
    Wtot[wave][lane] = Wl;
    __syncthreads();
    float O = cs2_carry, Wall = 0.f;
    for (int w = 0; w < NW; ++w) {
      float t = Wtot[w][lane];
      if (w < wave) O += t;
      Wall += t;
    }
    float Vl = 0.f;
#pragma unroll
    for (int k = 0; k < SPW; ++k) {
      float rcpA = fminf(fexp2(-(O + P[k])), RCPEPS);
      float gb = sg[dl * LCP + base + k] * sxpT[(1 + s) * PSX + base + k];
      Vl = fmaf(gb, rcpA, Vl);
    }
    Vtot[wave][lane] = Vl;
    __syncthreads();
    float SO = S_carry, Vall = 0.f;
    for (int w = 0; w < NW; ++w) {
      float tv = Vtot[w][lane];
      if (w < wave) SO += tv;
      Vall += tv;
    }
    float S = SO;
#pragma unroll
    for (int k = 0; k < SPW; ++k) {
      float xk = O + P[k];
      float rcpA = fminf(fexp2(-xk), RCPEPS);
      float aprev = fexp2(xk);
      float gb = sg[dl * LCP + base + k] * sxpT[(1 + s) * PSX + base + k];
      S = fmaf(gb, rcpA, S);
      float h = aprev * S;
      float contrib = sxpT[(17 + s) * PSX + base + k] * h;
      contrib += __shfl_xor(contrib, 8);
      contrib += __shfl_xor(contrib, 4);
      contrib += __shfl_xor(contrib, 2);
      contrib += __shfl_xor(contrib, 1);
      if (s == 0)
        sys[dl * LCP + base + k] = contrib + Dd * sxs[dl * LCP + base + k];
    }
    cs2_carry += Wall;
    S_carry += Vall;
    __syncthreads();
    // ---- store: gate with silu(z) from zT row (coalesced), in place ----
    for (int slot = tid; slot < 4 * (LC / 8); slot += 1024) {
      int c = slot >> 6, seg = slot & 63;
      bf16 zt[8];
      *(uint4*)zt = *(const uint4*)(zT + (size_t)(d0 + c) * L_SEQ + l0 + seg * 8);
      bf16 tmp[8];
#pragma unroll
      for (int j = 0; j < 8; ++j) {
        float yv = sys[c * LCP + seg * 8 + j];
        float zv = __bfloat162float(zt[j]);
        tmp[j] = __float2bfloat16(yv * zv * frcp(1.f + fexp2(-zv * LOG2E)));
      }
      u32x4v vv;
      vv.x = ((unsigned int*)tmp)[0]; vv.y = ((unsigned int*)tmp)[1];
      vv.z = ((unsigned int*)tmp)[2]; vv.w = ((unsigned int*)tmp)[3];
      __builtin_nontemporal_store(vv,
          (u32x4v*)(xsT + (size_t)(d0 + c) * L_SEQ + l0 + seg * 8));
    }
    // no trailing barrier: store (reads sys) and next staging (writes
    // sxpT/sxs) touch disjoint LDS; next readers are behind 2 barriers.
  }
}

// ---------- gemm2: out[l][n] = ys @ W_out, self-staging ----------
// A = gated ysT[d][l] (transpose-staged), B = W_out[d][n] fp32
// (transpose-cast-staged). Tile 64lx64n, K=DI, 32/step. grid (DM/64, L/64).
__global__ __launch_bounds__(256)
void gemm2_kernel(const bf16* __restrict__ ysT, const float* __restrict__ W_out,
                  float* __restrict__ out) {
  __shared__ __align__(16) bf16 As[64 * 34];
  __shared__ __align__(16) bf16 Bs[64 * 34];
  const int tid = threadIdx.x;
  const int wave = tid >> 6, lane = tid & 63;
  const int q = lane >> 4, r = lane & 15;
  const int wr = wave >> 1, wc = wave & 1;
  const int row0 = blockIdx.y * 64, col0 = blockIdx.x * 64;
  const int dr = tid >> 3, sg = tid & 7;  // dr: k-row 0..31, sg: 8-col group
  f32x4v acc[2][2] = {};
  for (int k0 = 0; k0 < DI; k0 += 32) {
    // A: ysT[k0+dr][row0 + sg*8 .. +8] -> As[l][34] transposed
    {
      bf16 t[8];
      *(uint4*)t = *(const uint4*)(ysT + (size_t)(k0 + dr) * L_SEQ + row0 + sg * 8);
#pragma unroll
      for (int i = 0; i < 8; ++i) As[(sg * 8 + i) * 34 + dr] = t[i];
    }
    // B: W_out[k0+dr][col0 + sg*8 .. +8] fp32 -> Bs[n][34] transposed+cast
    {
      float v[8];
      load8(W_out + (size_t)(k0 + dr) * DM + col0 + sg * 8, v);
#pragma unroll
      for (int i = 0; i < 8; ++i) Bs[(sg * 8 + i) * 34 + dr] = __float2bfloat16(v[i]);
    }
    __syncthreads();
    bf16x8v a[2], b[2];
#pragma unroll
    for (int m = 0; m < 2; ++m)
      a[m] = *(const bf16x8v*)&As[(wr * 32 + m * 16 + r) * 34 + q * 8];
#pragma unroll
    for (int n = 0; n < 2; ++n)
      b[n] = *(const bf16x8v*)&Bs[(wc * 32 + n * 16 + r) * 34 + q * 8];
#pragma unroll
    for (int m = 0; m < 2; ++m)
#pragma unroll
      for (int n = 0; n < 2; ++n)
        acc[m][n] = __builtin_amdgcn_mfma_f32_16x16x32_bf16(a[m], b[n],
                                                            acc[m][n], 0, 0, 0);
    __syncthreads();
  }
#pragma unroll
  for (int m = 0; m < 2; ++m)
#pragma unroll
    for (int n = 0; n < 2; ++n)
#pragma unroll
      for (int reg = 0; reg < 4; ++reg) {
        int mm = row0 + wr * 32 + m * 16 + q * 4 + reg;
        int nn = col0 + wc * 32 + n * 16 + r;
        out[(size_t)mm * DM + nn] = acc[m][n][reg];
      }
}

extern "C" void kernel_launch(void* const* d_in, const int* in_sizes, int n_in,
                              void* d_out, int out_size, void* d_ws, size_t ws_size,
                              hipStream_t stream) {
  const float* x       = (const float*)d_in[0];
  const float* W_in    = (const float*)d_in[1];
  const float* conv_w  = (const float*)d_in[2];
  const float* conv_b  = (const float*)d_in[3];
  const float* W_xproj = (const float*)d_in[4];
  const float* dt_w    = (const float*)d_in[5];
  const float* dt_b    = (const float*)d_in[6];
  const float* A_log   = (const float*)d_in[7];
  const float* Dvec    = (const float*)d_in[8];
  const float* W_out   = (const float*)d_in[9];
  float* out = (float*)d_out;

  char* ws = (char*)d_ws;
  const size_t MB = 1024 * 1024;
  bf16* xc    = (bf16*)(ws);             // [2048][1024] x-half (ld 1024)
  bf16* zT    = (bf16*)(ws + 4 * MB);    // [1024][2048] z transposed
  bf16* buf1  = (bf16*)(ws + 8 * MB);    // [2048][1024] xs for xproj
  bf16* WinT  = (bf16*)(ws + 12 * MB);   // [2048][512] (dead after gemm1)
  bf16* xbf   = (bf16*)(ws + 14 * MB);   // [2048][512] x cast (dead after gemm1)
  bf16* xsT   = (bf16*)(ws + 12 * MB);   // [1024][2048] overlays WinT+xbf
  float* xpcT = (float*)(ws + 16 * MB);  // [33][2048]

  // 1) prep: WinT = W_in^T bf16 (1024 blocks) + xbf = bf16(x) (512 blocks)
  prep_kernel<<<dim3(1536), 256, 0, stream>>>(W_in, WinT, x, xbf);
  // 2) gemm1: x-half -> xc, z-half -> zT (transposed)
  gemm1_kernel<<<dim3(2 * DI / 128, L_SEQ / 128), 256, 0, stream>>>(
      xbf, WinT, xc, zT);
  // 3) conv + silu -> buf1[l][d] AND xsT[d][l]; zeroes xpcT
  conv_silu_dual<<<dim3(DI / 64, L_SEQ / 64), 256, 0, stream>>>(
      xc, conv_w, conv_b, buf1, xsT, xpcT);
  // 4) xpcT += (xs @ W_xproj)^T  (split-K, 256 blocks)
  gemm_xproj_sk<<<dim3(8, L_SEQ / 64), 256, 0, stream>>>(buf1, W_xproj, xpcT);
  // 5) scan + fused gate: gated ysT in place over xsT
  scan_kernel<<<DI / 4, 1024, 0, stream>>>(xsT, xpcT, zT, dt_w, dt_b, A_log, Dvec);
  // 6) gemm2: out = ys @ W_out (self-staging: A from ysT, B from W_out fp32)
  gemm2_kernel<<<dim3(DM / 64, L_SEQ / 64), 256, 0, stream>>>(xsT, W_out, out);
}

// Round 10
// 191.513 us; speedup vs baseline: 1.0367x; 1.0367x over previous
//
#include <hip/hip_runtime.h>
#include <hip/hip_bf16.h>

// SelectiveSSM: B=1, L=2048, D_MODEL=512, D_INNER=1024, D_STATE=16, D_CONV=4
// ESTABLISHED: inputs fp32, d_out fp32, ws >= 17.05MB (R6 fp32 path ran).
// R17 (216us): scan serial-chain fix (exclusive log-prefix P[k] in regs).
// R20 (221us): scan floor 62us, no spill (VGPR 64). R21 (218us): dbuf
// gload_lds GEMMs -> GEMM bodies never the non-scan bulk.
// R22/R23 (190us, BEST): 9->7 dispatches (prep merge, gate+WT merge, xproj
// split-K 256 blocks) -> per-dispatch overhead ~6-12us confirmed.
// R24 (197us, FAILED): xproj fused into conv tail (+13us serial > boundary).
// R25 (198us, FAILED): gate fused into scan + self-staging gemm2 (lost
// gload_lds dbuf; scalar ds_write transpose staging = R15 lesson again).
// R26: REVERT to R23 exactly. Plateau of the profitable move set: scan
// latency-bound floor (5 attempts, 62-71us band), GEMMs non-dominant,
// fusion space exhausted with 2 measured regressions on both sides.
// ws 17.0MB: xz 8MB@0 | buf1 4MB@8 | 12-16MB: WinT 2MB + xbf 2MB@14 -> xsT
// 4MB | xpcT 264KB@16MB -> WoutT 1MB@16MB (after scan).

#define L_SEQ 2048
#define DM 512
#define DI 1024
#define DS 16
#define NXP 33
#define EPS 1e-10f
#define RCPEPS 1e10f
#define LOG2E 1.44269504088896340736f
#define LN2 0.69314718055994530942f
#define LOG2EPS -33.219280948873623478f  // log2(1e-10)

typedef __hip_bfloat16 bf16;
typedef __attribute__((ext_vector_type(8))) short bf16x8v;
typedef __attribute__((ext_vector_type(4))) float f32x4v;
typedef __attribute__((ext_vector_type(4))) unsigned int u32x4v;

__device__ __forceinline__ void st1(float* p, float v) { *p = v; }
__device__ __forceinline__ void st1(bf16* p, float v) { *p = __float2bfloat16(v); }

__device__ __forceinline__ float fexp2(float x) { return __builtin_amdgcn_exp2f(x); }
__device__ __forceinline__ float frcp(float x) { return __builtin_amdgcn_rcpf(x); }

__device__ __forceinline__ void load8(const float* p, float* v) {
  float4 a = *(const float4*)p;
  float4 b = *(const float4*)(p + 4);
  v[0] = a.x; v[1] = a.y; v[2] = a.z; v[3] = a.w;
  v[4] = b.x; v[5] = b.y; v[6] = b.z; v[7] = b.w;
}

// ---------- prep: W_in^T (blocks 0..1023) + x cast (1024..1535) ----------
__global__ __launch_bounds__(256)
void prep_kernel(const float* __restrict__ W_in, bf16* __restrict__ WinT,
                 const float* __restrict__ x, bf16* __restrict__ xbf) {
  __shared__ float tile[32][33];
  int b = blockIdx.x;
  if (b < 1024) {
    int c0 = (b & 63) * 32, r0 = (b >> 6) * 32;  // C=2048 (64 tiles), R=512 (16)
    int tx = threadIdx.x & 31, ty = threadIdx.x >> 5;
#pragma unroll
    for (int i = 0; i < 4; ++i) {
      int rr = ty + i * 8;
      tile[rr][tx] = W_in[(size_t)(r0 + rr) * (2 * DI) + c0 + tx];
    }
    __syncthreads();
#pragma unroll
    for (int i = 0; i < 4; ++i) {
      int cc = ty + i * 8;
      WinT[(size_t)(c0 + cc) * DM + r0 + tx] = __float2bfloat16(tile[tx][cc]);
    }
  } else {
    int i = (b - 1024) * 256 + threadIdx.x;  // < 131072 = L*DM/8 exactly
    float v[8];
    load8(x + (size_t)i * 8, v);
    bf16 o[8];
#pragma unroll
    for (int j = 0; j < 8; ++j) o[j] = __float2bfloat16(v[j]);
    *(uint4*)(xbf + (size_t)i * 8) = *(uint4*)o;
  }
}

// ---------- 2-phase double-buffered gload_lds GEMM (R21-proven) ----------
// C[M][N] = A[M][K] @ BT[N][K]^T. A,BT bf16. 256 thr = 4 waves (2x2).
template <int WM, int WN, typename TC>
__global__ __launch_bounds__(256)
void gemm_gl(const bf16* __restrict__ A, const bf16* __restrict__ BT,
             TC* __restrict__ C, int K, int lda, int ldc) {
  constexpr int BM = 2 * WM * 16, BN = 2 * WN * 16;
  __shared__ __align__(16) bf16 As[2][BM * 32];
  __shared__ __align__(16) bf16 Bs[2][BN * 32];
  const int tid = threadIdx.x;
  const int wave = tid >> 6, lane = tid & 63;
  const int q = lane >> 4, r = lane & 15;
  const int wr = wave >> 1, wc = wave & 1;
  const int row0 = blockIdx.y * BM, col0 = blockIdx.x * BN;
  f32x4v acc[WM][WN] = {};
  const int nt = K / 32;

  auto stage = [&](int buf, int t) {
    int k0 = t * 32;
#pragma unroll
    for (int i = 0; i < BM / 64; ++i) {
      int slot = tid + i * 256;
      int row = slot >> 2, seg = slot & 3;
      __builtin_amdgcn_global_load_lds(
          (const __attribute__((address_space(1))) void*)(
              A + (size_t)(row0 + row) * lda + k0 + seg * 8),
          (__attribute__((address_space(3))) void*)&As[buf][row * 32 + seg * 8],
          16, 0, 0);
    }
#pragma unroll
    for (int i = 0; i < BN / 64; ++i) {
      int slot = tid + i * 256;
      int row = slot >> 2, seg = slot & 3;
      __builtin_amdgcn_global_load_lds(
          (const __attribute__((address_space(1))) void*)(
              BT + (size_t)(col0 + row) * K + k0 + seg * 8),
          (__attribute__((address_space(3))) void*)&Bs[buf][row * 32 + seg * 8],
          16, 0, 0);
    }
  };

  stage(0, 0);
  __syncthreads();
  int cur = 0;
  for (int t = 0; t < nt; ++t) {
    if (t + 1 < nt) stage(cur ^ 1, t + 1);
    bf16x8v a[WM], b[WN];
#pragma unroll
    for (int m = 0; m < WM; ++m)
      a[m] = *(const bf16x8v*)&As[cur][(wr * WM * 16 + m * 16 + r) * 32 + q * 8];
#pragma unroll
    for (int n = 0; n < WN; ++n)
      b[n] = *(const bf16x8v*)&Bs[cur][(wc * WN * 16 + n * 16 + r) * 32 + q * 8];
#pragma unroll
    for (int m = 0; m < WM; ++m)
#pragma unroll
      for (int n = 0; n < WN; ++n)
        acc[m][n] = __builtin_amdgcn_mfma_f32_16x16x32_bf16(a[m], b[n],
                                                            acc[m][n], 0, 0, 0);
    __syncthreads();
    cur ^= 1;
  }
#pragma unroll
  for (int m = 0; m < WM; ++m)
#pragma unroll
    for (int n = 0; n < WN; ++n)
#pragma unroll
      for (int reg = 0; reg < 4; ++reg) {
        int mm = row0 + wr * WM * 16 + m * 16 + q * 4 + reg;
        int nn = col0 + wc * WN * 16 + n * 16 + r;
        st1(C + (size_t)mm * ldc + nn, acc[m][n][reg]);
      }
}

// ---------- xproj split-K: xpcT[j][l] += partial over K-chunk ----------
// grid (8, 32): blockIdx.x = 128-wide K chunk, blockIdx.y = 64-row l tile.
// xpcT must be zeroed beforehand (conv does it).
__global__ __launch_bounds__(256)
void gemm_xproj_sk(const bf16* __restrict__ A, const float* __restrict__ Wx,
                   float* __restrict__ xpcT) {
  __shared__ __align__(16) bf16 As[64 * 40];
  __shared__ __align__(16) bf16 Bs[64 * 40];
  const int tid = threadIdx.x;
  const int wave = tid >> 6, lane = tid & 63;
  const int q = lane >> 4, r = lane & 15;
  const int row0 = blockIdx.y * 64;
  const int kb = blockIdx.x * 128;
  const int srow = tid >> 2, sseg = tid & 3;
  f32x4v acc[4] = {};
  for (int k0 = kb; k0 < kb + 128; k0 += 32) {
    *(uint4*)&As[srow * 40 + sseg * 8] =
        *(const uint4*)(A + (size_t)(row0 + srow) * DI + k0 + sseg * 8);
    int k = tid >> 3, n0 = (tid & 7) * 8;
#pragma unroll
    for (int j = 0; j < 8; ++j) {
      int n = n0 + j;
      float v = (n < NXP) ? Wx[(size_t)(k0 + k) * NXP + n] : 0.f;
      Bs[n * 40 + k] = __float2bfloat16(v);
    }
    __syncthreads();
    bf16x8v a = *(const bf16x8v*)&As[(wave * 16 + r) * 40 + q * 8];
#pragma unroll
    for (int j = 0; j < 4; ++j) {
      bf16x8v b = *(const bf16x8v*)&Bs[(j * 16 + r) * 40 + q * 8];
      acc[j] = __builtin_amdgcn_mfma_f32_16x16x32_bf16(a, b, acc[j], 0, 0, 0);
    }
    __syncthreads();
  }
#pragma unroll
  for (int j = 0; j < 4; ++j)
#pragma unroll
    for (int reg = 0; reg < 4; ++reg) {
      int m = row0 + wave * 16 + q * 4 + reg;
      int n = j * 16 + r;
      if (n < NXP) atomicAdd(&xpcT[(size_t)n * L_SEQ + m], acc[j][reg]);
    }
}

// ---------- conv + silu, dual-layout output; also zeroes xpcT ----------
__global__ __launch_bounds__(256)
void conv_silu_dual(const bf16* __restrict__ xz, const float* __restrict__ conv_w,
                    const float* __restrict__ conv_b, bf16* __restrict__ xs,
                    bf16* __restrict__ xsT, float* __restrict__ xpcT) {
  __shared__ bf16 tile[67][72];   // rows l0-3 .. l0+63
  __shared__ bf16 sout[64][72];   // [d][l]
  const int tid = threadIdx.x;
  const int d0 = blockIdx.x * 64, l0 = blockIdx.y * 64;
  // zero xpcT slice (512 blocks x 132 = 67584 = 33*2048)
  {
    int zb = blockIdx.y * gridDim.x + blockIdx.x;
    if (tid < 132) xpcT[(size_t)zb * 132 + tid] = 0.f;
  }
  // stage 67 rows x 64 cols
  for (int slot = tid; slot < 67 * 8; slot += 256) {
    int rr = slot >> 3, seg = slot & 7;
    int l = l0 - 3 + rr;
    uint4 v = {0, 0, 0, 0};
    if (l >= 0) v = *(const uint4*)(xz + (size_t)l * (2 * DI) + d0 + seg * 8);
    *(uint4*)&tile[rr][seg * 8] = v;
  }
  __syncthreads();
  {
    int lr = tid >> 3, c0t = (tid & 7) * 8;
#pragma unroll
    for (int half = 0; half < 2; ++half) {
      int lrow = lr + half * 32;
      bf16 o[8];
#pragma unroll
      for (int j = 0; j < 8; ++j) {
        int c = c0t + j;
        float acc = conv_b[d0 + c];
#pragma unroll
        for (int k = 0; k < 4; ++k)
          acc = fmaf(__bfloat162float(tile[lrow + k][c]), conv_w[(d0 + c) * 4 + k], acc);
        float v = acc / (1.f + __expf(-acc));
        o[j] = __float2bfloat16(v);
        sout[c][lrow] = o[j];
      }
      *(uint4*)(xs + (size_t)(l0 + lrow) * DI + d0 + c0t) = *(uint4*)o;
    }
  }
  __syncthreads();
  for (int slot = tid; slot < 64 * 8; slot += 256) {
    int dd = slot >> 3, seg = slot & 7;
    *(uint4*)(xsT + (size_t)(d0 + dd) * L_SEQ + l0 + seg * 8) =
        *(uint4*)&sout[dd][seg * 8];
  }
}

// ---------- gate (by<16) + W_out transpose (by>=16) ----------
// gate: ys[l][d] = yT[d][l] * silu(z[l][d]). transpose: WoutT[n][k]=W_out[k][n].
__global__ __launch_bounds__(256)
void gate_wt_kernel(const bf16* __restrict__ yT, const bf16* __restrict__ zbuf,
                    int ldz, bf16* __restrict__ ys,
                    const float* __restrict__ W_out, bf16* __restrict__ WoutT) {
  __shared__ bf16 tile[64][72];
  __shared__ float ttile[32][33];
  if (blockIdx.y >= 16) {
    int tb = (blockIdx.y - 16) * 32 + blockIdx.x;  // 0..511
    int c0 = (tb & 15) * 32, r0 = (tb >> 4) * 32;  // C=DM (16 tiles), R=DI (32)
    int tx = threadIdx.x & 31, ty = threadIdx.x >> 5;
#pragma unroll
    for (int i = 0; i < 4; ++i) {
      int rr = ty + i * 8;
      ttile[rr][tx] = W_out[(size_t)(r0 + rr) * DM + c0 + tx];
    }
    __syncthreads();
#pragma unroll
    for (int i = 0; i < 4; ++i) {
      int cc = ty + i * 8;
      WoutT[(size_t)(c0 + cc) * DI + r0 + tx] = __float2bfloat16(ttile[tx][cc]);
    }
    return;
  }
  int d0 = blockIdx.y * 64, l0 = blockIdx.x * 64;
#pragma unroll
  for (int it = 0; it < 2; ++it) {
    int slot = threadIdx.x + it * 256;
    int dd = slot >> 3, seg = slot & 7;
    *(uint4*)&tile[dd][seg * 8] = *(const uint4*)(yT + (size_t)(d0 + dd) * L_SEQ + l0 + seg * 8);
  }
  __syncthreads();
#pragma unroll
  for (int it = 0; it < 2; ++it) {
    int slot = threadIdx.x + it * 256;
    int ll = slot >> 3, seg = slot & 7;
    bf16 zt[8];
    *(uint4*)zt = *(const uint4*)(zbuf + (size_t)(l0 + ll) * ldz + d0 + seg * 8);
    bf16 o[8];
#pragma unroll
    for (int j = 0; j < 8; ++j) {
      float yv = __bfloat162float(tile[seg * 8 + j][ll]);
      float zv = __bfloat162float(zt[j]);
      o[j] = __float2bfloat16(yv * zv * frcp(1.f + fexp2(-zv * LOG2E)));
    }
    *(uint4*)(ys + (size_t)(l0 + ll) * DI + d0 + seg * 8) = *(uint4*)o;
  }
}

// ---------- chunk-parallel scan (R20-proven: ~63us, VGPR 64, no spill) ----------
#define LC 512
#define NW 16
#define SPW 32
#define PSX 513
#define LCP 516

__global__ __launch_bounds__(1024)
void scan_kernel(bf16* __restrict__ xsT, const float* __restrict__ xpcT,
                 const float* __restrict__ dt_w, const float* __restrict__ dt_b,
                 const float* __restrict__ A_log, const float* __restrict__ Dvec) {
  __shared__ float sxpT[NXP * PSX];
  __shared__ float sdt[4 * LCP], sg[4 * LCP], sxs[4 * LCP];
  __shared__ float sys[4 * LCP];
  __shared__ float Wtot[NW][64], Vtot[NW][64];
  const int tid = threadIdx.x;
  const int wave = tid >> 6, lane = tid & 63;
  const int s = lane & 15, dl = lane >> 4;
  const int d0 = blockIdx.x * 4;
  const int base = wave * SPW;
  const float As2 = -expf(A_log[s]) * LOG2E;
  const float Dd = Dvec[d0 + dl];
  float dtw[4], dtb[4];
#pragma unroll
  for (int c = 0; c < 4; ++c) {
    dtw[c] = dt_w[d0 + c];
    dtb[c] = dt_b[d0 + c];
  }
  float cs2_carry = 0.f, S_carry = 0.f;
  for (int l0 = 0; l0 < L_SEQ; l0 += LC) {
    for (int idx = tid; idx < NXP * LC; idx += 1024) {
      int u = __builtin_amdgcn_readfirstlane(idx & ~63);
      int j = u >> 9, lb = u & (LC - 1);
      const float* gp = xpcT + (size_t)j * L_SEQ + l0 + lb + lane;
      __builtin_amdgcn_global_load_lds(
          (const __attribute__((address_space(1))) void*)gp,
          (__attribute__((address_space(3))) void*)&sxpT[j * PSX + lb], 4, 0, 0);
    }
    for (int slot = tid; slot < 4 * (LC / 8); slot += 1024) {
      int c = slot >> 6, seg = slot & 63;
      bf16 tmp[8];
      *(uint4*)tmp = *(const uint4*)(xsT + (size_t)(d0 + c) * L_SEQ + l0 + seg * 8);
#pragma unroll
      for (int j = 0; j < 8; ++j) sxs[c * LCP + seg * 8 + j] = __bfloat162float(tmp[j]);
    }
    __syncthreads();
    for (int idx = tid; idx < 4 * LC; idx += 1024) {
      int c = idx >> 9, i = idx & (LC - 1);
      float x0 = sxpT[i];
      float a = fmaf(x0, dtw[c], dtb[c]);
      float dt = __log2f(1.f + fexp2(a * LOG2E)) * LN2;
      sdt[c * LCP + i] = dt;
      sg[c * LCP + i] = dt * sxs[c * LCP + i];
    }
    __syncthreads();
    float P[SPW];
    float Wl = 0.f;
#pragma unroll
    for (int k = 0; k < SPW; ++k) {
      float u = sdt[dl * LCP + base + k] * As2;
      P[k] = Wl;
      Wl += fmaxf(u, LOG2EPS);
    }
    Wtot[wave][lane] = Wl;
    __syncthreads();
    float O = cs2_carry, Wall = 0.f;
    for (int w = 0; w < NW; ++w) {
      float t = Wtot[w][lane];
      if (w < wave) O += t;
      Wall += t;
    }
    float Vl = 0.f;
#pragma unroll
    for (int k = 0; k < SPW; ++k) {
      float rcpA = fminf(fexp2(-(O + P[k])), RCPEPS);
      float gb = sg[dl * LCP + base + k] * sxpT[(1 + s) * PSX + base + k];
      Vl = fmaf(gb, rcpA, Vl);
    }
    Vtot[wave][lane] = Vl;
    __syncthreads();
    float SO = S_carry, Vall = 0.f;
    for (int w = 0; w < NW; ++w) {
      float tv = Vtot[w][lane];
      if (w < wave) SO += tv;
      Vall += tv;
    }
    float S = SO;
#pragma unroll
    for (int k = 0; k < SPW; ++k) {
      float xk = O + P[k];
      float rcpA = fminf(fexp2(-xk), RCPEPS);
      float aprev = fexp2(xk);
      float gb = sg[dl * LCP + base + k] * sxpT[(1 + s) * PSX + base + k];
      S = fmaf(gb, rcpA, S);
      float h = aprev * S;
      float contrib = sxpT[(17 + s) * PSX + base + k] * h;
      contrib += __shfl_xor(contrib, 8);
      contrib += __shfl_xor(contrib, 4);
      contrib += __shfl_xor(contrib, 2);
      contrib += __shfl_xor(contrib, 1);
      if (s == 0)
        sys[dl * LCP + base + k] = contrib + Dd * sxs[dl * LCP + base + k];
    }
    cs2_carry += Wall;
    S_carry += Vall;
    __syncthreads();
    for (int slot = tid; slot < 4 * (LC / 8); slot += 1024) {
      int c = slot >> 6, seg = slot & 63;
      bf16 tmp[8];
#pragma unroll
      for (int j = 0; j < 8; ++j) tmp[j] = __float2bfloat16(sys[c * LCP + seg * 8 + j]);
      u32x4v vv;
      vv.x = ((unsigned int*)tmp)[0]; vv.y = ((unsigned int*)tmp)[1];
      vv.z = ((unsigned int*)tmp)[2]; vv.w = ((unsigned int*)tmp)[3];
      __builtin_nontemporal_store(vv,
          (u32x4v*)(xsT + (size_t)(d0 + c) * L_SEQ + l0 + seg * 8));
    }
    // no trailing barrier: store (reads sys) and next staging (writes
    // sxpT/sxs) touch disjoint LDS; next readers are behind 2 barriers.
  }
}

extern "C" void kernel_launch(void* const* d_in, const int* in_sizes, int n_in,
                              void* d_out, int out_size, void* d_ws, size_t ws_size,
                              hipStream_t stream) {
  const float* x       = (const float*)d_in[0];
  const float* W_in    = (const float*)d_in[1];
  const float* conv_w  = (const float*)d_in[2];
  const float* conv_b  = (const float*)d_in[3];
  const float* W_xproj = (const float*)d_in[4];
  const float* dt_w    = (const float*)d_in[5];
  const float* dt_b    = (const float*)d_in[6];
  const float* A_log   = (const float*)d_in[7];
  const float* Dvec    = (const float*)d_in[8];
  const float* W_out   = (const float*)d_in[9];
  float* out = (float*)d_out;

  char* ws = (char*)d_ws;
  const size_t MB = 1024 * 1024;
  bf16* xz    = (bf16*)(ws);             // [2048][2048]
  bf16* buf1  = (bf16*)(ws + 8 * MB);    // [2048][1024] xs, later gated ys
  bf16* WinT  = (bf16*)(ws + 12 * MB);   // [2048][512] (dead after gemm1)
  bf16* xbf   = (bf16*)(ws + 14 * MB);   // [2048][512] x cast (dead after gemm1)
  bf16* xsT   = (bf16*)(ws + 12 * MB);   // [1024][2048] overlays WinT+xbf
  float* xpcT = (float*)(ws + 16 * MB);  // [33][2048] (dead after scan)
  bf16* WoutT = (bf16*)(ws + 16 * MB);   // [512][1024] overlays dead xpcT

  // 1) prep: WinT = W_in^T bf16 (1024 blocks) + xbf = bf16(x) (512 blocks)
  prep_kernel<<<dim3(1536), 256, 0, stream>>>(W_in, WinT, x, xbf);
  // 2) xz = x @ W_in  (128x128 tile, grid 16x16 = 256 blocks)
  gemm_gl<4, 4, bf16><<<dim3(2 * DI / 128, L_SEQ / 128), 256, 0, stream>>>(
      xbf, WinT, xz, DM, DM, 2 * DI);
  // 3) conv + silu -> buf1[l][d] AND xsT[d][l]; zeroes xpcT  (WinT, xbf dead)
  conv_silu_dual<<<dim3(DI / 64, L_SEQ / 64), 256, 0, stream>>>(
      xz, conv_w, conv_b, buf1, xsT, xpcT);
  // 4) xpcT += (xs @ W_xproj)^T  (split-K, 256 blocks)
  gemm_xproj_sk<<<dim3(8, L_SEQ / 64), 256, 0, stream>>>(buf1, W_xproj, xpcT);
  // 5) scan: un-gated yT in place over xsT
  scan_kernel<<<DI / 4, 1024, 0, stream>>>(xsT, xpcT, dt_w, dt_b, A_log, Dvec);
  // 6) gate (512 blocks) + WoutT = W_out^T (512 blocks); xpcT dead -> WoutT
  gate_wt_kernel<<<dim3(L_SEQ / 64, 2 * DI / 64), 256, 0, stream>>>(
      xsT, xz + DI, 2 * DI, buf1, W_out, WoutT);
  // 7) out = ys @ W_out  (64x64 tile, grid 8x32 = 256 blocks)
  gemm_gl<2, 2, float><<<dim3(DM / 64, L_SEQ / 64), 256, 0, stream>>>(
      buf1, WoutT, out, DI, DI, DM);
}